// Round 1
// baseline (460.459 us; speedup 1.0000x reference)
//
#include <hip/hip_runtime.h>
#include <hip/hip_bf16.h>
#include <math.h>

#define B_ 32768
#define F_ 512
#define H_ 256
#define C_ 100
#define CP 112   // C padded to 7*16 for MFMA m-tiles
#define E_ 8

typedef __attribute__((ext_vector_type(8))) short bf16x8;
typedef __attribute__((ext_vector_type(4))) float f32x4;

__device__ __forceinline__ unsigned short f2b(float f) {
    unsigned int u = __float_as_uint(f);
    return (unsigned short)((u + 0x7fffu + ((u >> 16) & 1u)) >> 16);
}

__device__ __forceinline__ void gll16(const void* g, void* l) {
    __builtin_amdgcn_global_load_lds((__attribute__((address_space(1))) void*)(g),
                                     (__attribute__((address_space(3))) void*)(l),
                                     16, 0, 0);
}

// ---------------- K0b: W1 [E][F][H] f32 -> W1t [E][H][F] bf16 ----------------
__global__ __launch_bounds__(256) void k0_tr_w1(const float* __restrict__ W1,
                                                unsigned short* __restrict__ w1t) {
    __shared__ float tile[32][33];
    int e = blockIdx.z, fb = blockIdx.x * 32, hb = blockIdx.y * 32;
    int tx = threadIdx.x, ty = threadIdx.y;
    #pragma unroll
    for (int j = 0; j < 4; ++j)
        tile[ty + 8 * j][tx] = W1[((size_t)(e * F_ + fb + ty + 8 * j)) * H_ + hb + tx];
    __syncthreads();
    #pragma unroll
    for (int j = 0; j < 4; ++j)
        w1t[((size_t)(e * H_ + hb + ty + 8 * j)) * F_ + fb + tx] = f2b(tile[tx][ty + 8 * j]);
}

// ---------------- K0c: W2 [E][H][C] f32 -> W2t [E][CP][H] bf16 (zero-padded) ----------------
__global__ __launch_bounds__(256) void k0_cvt_w2(const float* __restrict__ W2,
                                                 unsigned short* __restrict__ w2t) {
    int idx = blockIdx.x * 256 + threadIdx.x;
    if (idx >= E_ * CP * H_) return;
    int e = idx / (CP * H_);
    int r = idx - e * (CP * H_);
    int c = r / H_, h = r - c * H_;
    float v = (c < C_) ? W2[((size_t)(e * H_ + h)) * C_ + c] : 0.0f;
    w2t[idx] = f2b(v);
}

// ---------------- K1: fp64 gating, top-2, part_sizes + fused x->bf16 convert ----------------
__global__ __launch_bounds__(256) void k1_gate(const float* __restrict__ x,
                                               const float* __restrict__ Wg,
                                               unsigned short* __restrict__ xb,
                                               int* __restrict__ routes,
                                               float* __restrict__ part) {
    __shared__ float sWg[F_ * E_];
    __shared__ int cnt[E_];
    int tid = threadIdx.x;
    for (int i = tid; i < F_ * E_; i += 256) sWg[i] = Wg[i];
    if (tid < E_) cnt[tid] = 0;
    __syncthreads();

    int r = tid >> 3, eidx = tid & 7;
    int row = blockIdx.x * 32 + r;
    const float* xr = x + (size_t)row * F_;
    double acc = 0.0;
    for (int f = 0; f < F_; f += 4) {
        float4 xv = *(const float4*)(xr + f);
        acc += (double)xv.x * (double)sWg[(f + 0) * 8 + eidx];
        acc += (double)xv.y * (double)sWg[(f + 1) * 8 + eidx];
        acc += (double)xv.z * (double)sWg[(f + 2) * 8 + eidx];
        acc += (double)xv.w * (double)sWg[(f + 3) * 8 + eidx];
    }
    // top-1 (ties -> lower index), butterfly within aligned groups of 8 lanes
    double v = acc; int ie = eidx;
    #pragma unroll
    for (int off = 1; off < 8; off <<= 1) {
        double ov = __shfl_xor(v, off);
        int oi = __shfl_xor(ie, off);
        if (ov > v || (ov == v && oi < ie)) { v = ov; ie = oi; }
    }
    int e1 = ie;
    double v2 = (eidx == e1) ? -1e300 : acc; int ie2 = eidx;
    #pragma unroll
    for (int off = 1; off < 8; off <<= 1) {
        double ov = __shfl_xor(v2, off);
        int oi = __shfl_xor(ie2, off);
        if (ov > v2 || (ov == v2 && oi < ie2)) { v2 = ov; ie2 = oi; }
    }
    int e2 = ie2;
    if (eidx == 0) {
        routes[row] = e1 | (e2 << 3);
        atomicAdd(&cnt[e1], 1);
        atomicAdd(&cnt[e2], 1);
    }
    __syncthreads();
    if (tid < E_) atomicAdd(&part[tid], (float)cnt[tid]);

    // fused x -> bf16 conversion: this block's 32 rows are L1/L2-hot from the
    // gate loop above; re-read coalesced, write xbf coalesced (replaces k0_cvt_x).
    const float4* xs = (const float4*)(x + (size_t)blockIdx.x * 32 * F_);
    ushort4* xd = (ushort4*)(xb + (size_t)blockIdx.x * 32 * F_);
    #pragma unroll
    for (int i = 0; i < 16; ++i) {
        float4 xv = xs[tid + i * 256];
        ushort4 o;
        o.x = f2b(xv.x); o.y = f2b(xv.y); o.z = f2b(xv.z); o.w = f2b(xv.w);
        xd[tid + i * 256] = o;
    }
}

// ---------------- K2: fused per-expert MLP ----------------
// Block: 256 thr (4 waves), 64 rows x expert e. LDS 64 KiB -> 2 blocks/CU.
// GEMM1: h[64x256] = relu(x_tile[64x512] @ W1[e]).
//   A (x tile): staged ONCE in prologue as 8 sub-tiles of [64 rows][8 swizzled
//     16B slots] (8 KiB each, 64 KiB total) via global_load_lds; ZERO barriers
//     and ZERO staging inside the K-loop.
//   B (w1t): read straight from global (L2-hot: 256 KiB shared by 512 blocks),
//     register double-buffered one half-step (K=32) ahead; 16 MFMAs of latency
//     cover per half-step.
// sH overlays [0,33792) after a single post-loop barrier.
// GEMM2: preds^T = W2(A, registers from global, dbuf over kc) @ h(B from sH).
__global__ __launch_bounds__(256, 2) void k2_moe(const unsigned short* __restrict__ xbf,
                                                 const unsigned short* __restrict__ w1t,
                                                 const unsigned short* __restrict__ w2t,
                                                 const float* __restrict__ b1,
                                                 const float* __restrict__ b2,
                                                 float* __restrict__ preds) {
    __shared__ __align__(16) char smem[65536];
    const int tid = threadIdx.x;
    const int w = tid >> 6, lane = tid & 63;
    const int q = lane >> 4, ln = lane & 15;
    const int e = blockIdx.y;
    const int rowBase = blockIdx.x * 64;

    // ---- prologue: stage the whole 64x512 A-tile (8 x 8KiB, swizzled slots) ----
    // lane l of wave w covers dest chunk rows w*8+sub (+32), slot l&7,
    // source chunk j8 = slot ^ (row&7)
    const int sub = lane >> 3;
    const int j8 = (lane & 7) ^ sub;
    const unsigned short* srcA0 = xbf + (size_t)(rowBase + w * 8 + sub) * F_ + 8 * j8;
    char* dstA = smem + w * 1024;
    #pragma unroll
    for (int kk = 0; kk < 8; ++kk) {
        gll16(srcA0 + kk * 64, dstA + kk * 8192);
        gll16(srcA0 + 32 * F_ + kk * 64, dstA + kk * 8192 + 4096);
    }

    // hoist bias1 (L2-hot)
    float bias1[4];
    #pragma unroll
    for (int nt = 0; nt < 4; ++nt) bias1[nt] = b1[e * H_ + w * 64 + nt * 16 + ln];

    f32x4 acc[4][4];
    #pragma unroll
    for (int i = 0; i < 4; ++i)
        #pragma unroll
        for (int j = 0; j < 4; ++j) acc[i][j] = (f32x4){0.f, 0.f, 0.f, 0.f};

    // B base: wave w owns h-cols [w*64, w*64+64); frag rows nt*16+ln, k-chunk q*8
    const unsigned short* bb = w1t + ((size_t)e * H_ + w * 64 + ln) * F_ + q * 8;
    bf16x8 bcur[4], bnxt[4];
    #pragma unroll
    for (int nt = 0; nt < 4; ++nt) bcur[nt] = *(const bf16x8*)(bb + nt * 16 * F_);

    __syncthreads();   // A-tile fully staged (drains the 16 gll16 + initial B loads)

    // ---- GEMM1 K-loop: 16 half-steps (K=32 each), no barriers, no staging ----
    #pragma unroll
    for (int h = 0; h < 16; ++h) {
        const int kk = h >> 1, ks = h & 1;
        if (h < 15) {
            const int off2 = ((h + 1) >> 1) * 64 + ((h + 1) & 1) * 32;
            #pragma unroll
            for (int nt = 0; nt < 4; ++nt)
                bnxt[nt] = *(const bf16x8*)(bb + nt * 16 * F_ + off2);
        }
        const int slot = ((ks * 4 + q) ^ (ln & 7)) * 16;
        bf16x8 af[4];
        #pragma unroll
        for (int mt = 0; mt < 4; ++mt)
            af[mt] = *(const bf16x8*)(smem + kk * 8192 + (mt * 16 + ln) * 128 + slot);
        #pragma unroll
        for (int mt = 0; mt < 4; ++mt)
            #pragma unroll
            for (int nt = 0; nt < 4; ++nt)
                acc[mt][nt] = __builtin_amdgcn_mfma_f32_16x16x32_bf16(af[mt], bcur[nt], acc[mt][nt], 0, 0, 0);
        #pragma unroll
        for (int nt = 0; nt < 4; ++nt) bcur[nt] = bnxt[nt];
    }

    __syncthreads();   // all waves done reading A-tiles; safe to overlay sH

    // prefetch W2 kc=0 fragments (L2-hot) -> latency hides under the sH writes
    const unsigned short* w2base = w2t + ((size_t)e * CP + ln) * H_ + q * 8;
    bf16x8 wreg[2][7];
    #pragma unroll
    for (int mt = 0; mt < 7; ++mt)
        wreg[0][mt] = *(const bf16x8*)(w2base + mt * 16 * H_);

    // epilogue GEMM1: +b1, relu -> sH (bf16), row stride 528 B
    #pragma unroll
    for (int mt = 0; mt < 4; ++mt)
        #pragma unroll
        for (int nt = 0; nt < 4; ++nt)
            #pragma unroll
            for (int r2 = 0; r2 < 4; ++r2) {
                int rr = mt * 16 + q * 4 + r2;
                int col = w * 64 + nt * 16 + ln;
                float v = fmaxf(acc[mt][nt][r2] + bias1[nt], 0.0f);
                *(unsigned short*)(smem + rr * 528 + col * 2) = f2b(v);
            }

    f32x4 acc2[7];
    #pragma unroll
    for (int i = 0; i < 7; ++i) acc2[i] = (f32x4){0.f, 0.f, 0.f, 0.f};
    const int offH = (w * 16 + ln) * 528 + q * 16;

    __syncthreads();   // sH fully written

    #pragma unroll
    for (int kc = 0; kc < 8; ++kc) {
        const int cur = kc & 1, nxt = cur ^ 1;
        if (kc < 7) {
            #pragma unroll
            for (int mt = 0; mt < 7; ++mt)
                wreg[nxt][mt] = *(const bf16x8*)(w2base + mt * 16 * H_ + (kc + 1) * 32);
        }
        bf16x8 hb = *(const bf16x8*)(smem + offH + kc * 64);
        #pragma unroll
        for (int mt = 0; mt < 7; ++mt)
            acc2[mt] = __builtin_amdgcn_mfma_f32_16x16x32_bf16(wreg[cur][mt], hb, acc2[mt], 0, 0, 0);
    }

    // write preds[e][row][c]: lane holds c = mt*16 + q*4 + {0..3}, row = rowBase + w*16 + ln
    int row = rowBase + w * 16 + ln;
    #pragma unroll
    for (int mt = 0; mt < 7; ++mt) {
        int c0 = mt * 16 + q * 4;
        if (c0 + 3 < C_) {
            f32x4 bias = *(const f32x4*)(b2 + e * C_ + c0);
            f32x4 o = acc2[mt] + bias;
            *(f32x4*)(preds + ((size_t)e * B_ + row) * C_ + c0) = o;
        }
    }
}

// ---------------- K3: softmax(preds[e]) for routed experts, combine ----------------
__global__ __launch_bounds__(256) void k3_combine(const float* __restrict__ preds,
                                                  const int* __restrict__ routes,
                                                  float* __restrict__ combined) {
    __shared__ float pbuf[4][104];
    int tid = threadIdx.x, wv = tid >> 6, lane = tid & 63;
    int row = blockIdx.x * 2 + (wv >> 1);
    int rt = routes[row];
    int e = (wv & 1) ? ((rt >> 3) & 7) : (rt & 7);
    const float* pr = preds + ((size_t)e * B_ + row) * C_;
    float a0 = (lane < C_) ? pr[lane] : -1e30f;
    float a1 = (lane + 64 < C_) ? pr[lane + 64] : -1e30f;
    float m = fmaxf(a0, a1);
    #pragma unroll
    for (int off = 32; off; off >>= 1) m = fmaxf(m, __shfl_xor(m, off));
    float s0 = (lane < C_) ? expf(a0 - m) : 0.f;
    float s1 = (lane + 64 < C_) ? expf(a1 - m) : 0.f;
    float s = s0 + s1;
    #pragma unroll
    for (int off = 32; off; off >>= 1) s += __shfl_xor(s, off);
    float inv = 0.5f / s;
    if (lane < C_) pbuf[wv][lane] = s0 * inv;
    if (lane + 64 < C_) pbuf[wv][lane + 64] = s1 * inv;
    __syncthreads();
    if (tid < C_)
        combined[(size_t)(blockIdx.x * 2) * C_ + tid] = pbuf[0][tid] + pbuf[1][tid];
    else if (tid >= 128 && tid < 128 + C_)
        combined[(size_t)(blockIdx.x * 2 + 1) * C_ + (tid - 128)] = pbuf[2][tid - 128] + pbuf[3][tid - 128];
}

extern "C" void kernel_launch(void* const* d_in, const int* in_sizes, int n_in,
                              void* d_out, int out_size, void* d_ws, size_t ws_size,
                              hipStream_t stream) {
    (void)in_sizes; (void)n_in; (void)out_size;
    const float* x  = (const float*)d_in[0];
    const float* W1 = (const float*)d_in[1];
    const float* b1 = (const float*)d_in[2];
    const float* W2 = (const float*)d_in[3];
    const float* b2 = (const float*)d_in[4];
    const float* Wg = (const float*)d_in[5];
    // d_in[6] = k (always 2 per setup)

    float* out = (float*)d_out;
    float* combined = out;                                          // [B][C]
    float* preds = out + (size_t)B_ * C_;                           // [E][B][C]
    float* part  = out + (size_t)B_ * C_ + (size_t)E_ * B_ * C_;    // [E]

    char* ws = (char*)d_ws;
    unsigned short* xbf = (unsigned short*)ws;                      // 33,554,432 B
    unsigned short* w1t = (unsigned short*)(ws + 33554432);         //  2,097,152 B
    unsigned short* w2t = (unsigned short*)(ws + 35651584);         //    458,752 B
    int* routes = (int*)(ws + 36110336);                            //    131,072 B
    if (ws_size < 36241408) return;  // need ~36.3 MB scratch

    hipMemsetAsync(part, 0, E_ * sizeof(float), stream);
    k0_tr_w1<<<dim3(F_ / 32, H_ / 32, E_), dim3(32, 8), 0, stream>>>(W1, w1t);
    k0_cvt_w2<<<(E_ * CP * H_ + 255) / 256, 256, 0, stream>>>(W2, w2t);
    k1_gate<<<B_ / 32, 256, 0, stream>>>(x, Wg, xbf, routes, part);
    k2_moe<<<dim3(B_ / 64, E_), 256, 0, stream>>>(xbf, w1t, w2t, b1, b2, preds);
    k3_combine<<<B_ / 2, 256, 0, stream>>>(preds, routes, combined);
}

// Round 3
// 436.995 us; speedup vs baseline: 1.0537x; 1.0537x over previous
//
#include <hip/hip_runtime.h>
#include <hip/hip_bf16.h>
#include <math.h>

#define B_ 32768
#define F_ 512
#define H_ 256
#define C_ 100
#define CP 112   // C padded to 7*16 for MFMA m-tiles
#define E_ 8

typedef __attribute__((ext_vector_type(8))) short bf16x8;
typedef __attribute__((ext_vector_type(4))) float f32x4;

__device__ __forceinline__ unsigned short f2b(float f) {
    unsigned int u = __float_as_uint(f);
    return (unsigned short)((u + 0x7fffu + ((u >> 16) & 1u)) >> 16);
}

__device__ __forceinline__ void gll16(const void* g, void* l) {
    __builtin_amdgcn_global_load_lds((__attribute__((address_space(1))) void*)(g),
                                     (__attribute__((address_space(3))) void*)(l),
                                     16, 0, 0);
}

// ---------------- K0b: W1 [E][F][H] f32 -> W1t [E][H][F] bf16 ----------------
__global__ __launch_bounds__(256) void k0_tr_w1(const float* __restrict__ W1,
                                                unsigned short* __restrict__ w1t) {
    __shared__ float tile[32][33];
    int e = blockIdx.z, fb = blockIdx.x * 32, hb = blockIdx.y * 32;
    int tx = threadIdx.x, ty = threadIdx.y;
    #pragma unroll
    for (int j = 0; j < 4; ++j)
        tile[ty + 8 * j][tx] = W1[((size_t)(e * F_ + fb + ty + 8 * j)) * H_ + hb + tx];
    __syncthreads();
    #pragma unroll
    for (int j = 0; j < 4; ++j)
        w1t[((size_t)(e * H_ + hb + ty + 8 * j)) * F_ + fb + tx] = f2b(tile[tx][ty + 8 * j]);
}

// ---------------- K0c: W2 [E][H][C] f32 -> W2t [E][CP][H] bf16 (zero-padded) ----------------
__global__ __launch_bounds__(256) void k0_cvt_w2(const float* __restrict__ W2,
                                                 unsigned short* __restrict__ w2t) {
    int idx = blockIdx.x * 256 + threadIdx.x;
    if (idx >= E_ * CP * H_) return;
    int e = idx / (CP * H_);
    int r = idx - e * (CP * H_);
    int c = r / H_, h = r - c * H_;
    float v = (c < C_) ? W2[((size_t)(e * H_ + h)) * C_ + c] : 0.0f;
    w2t[idx] = f2b(v);
}

// ---------------- K1: fp64 gating, top-2, part_sizes + fused x->bf16 convert ----------------
__global__ __launch_bounds__(256) void k1_gate(const float* __restrict__ x,
                                               const float* __restrict__ Wg,
                                               unsigned short* __restrict__ xb,
                                               int* __restrict__ routes,
                                               float* __restrict__ part) {
    __shared__ float sWg[F_ * E_];
    __shared__ int cnt[E_];
    int tid = threadIdx.x;
    for (int i = tid; i < F_ * E_; i += 256) sWg[i] = Wg[i];
    if (tid < E_) cnt[tid] = 0;
    __syncthreads();

    int r = tid >> 3, eidx = tid & 7;
    int row = blockIdx.x * 32 + r;
    const float* xr = x + (size_t)row * F_;
    double acc = 0.0;
    for (int f = 0; f < F_; f += 4) {
        float4 xv = *(const float4*)(xr + f);
        acc += (double)xv.x * (double)sWg[(f + 0) * 8 + eidx];
        acc += (double)xv.y * (double)sWg[(f + 1) * 8 + eidx];
        acc += (double)xv.z * (double)sWg[(f + 2) * 8 + eidx];
        acc += (double)xv.w * (double)sWg[(f + 3) * 8 + eidx];
    }
    // top-1 (ties -> lower index), butterfly within aligned groups of 8 lanes
    double v = acc; int ie = eidx;
    #pragma unroll
    for (int off = 1; off < 8; off <<= 1) {
        double ov = __shfl_xor(v, off);
        int oi = __shfl_xor(ie, off);
        if (ov > v || (ov == v && oi < ie)) { v = ov; ie = oi; }
    }
    int e1 = ie;
    double v2 = (eidx == e1) ? -1e300 : acc; int ie2 = eidx;
    #pragma unroll
    for (int off = 1; off < 8; off <<= 1) {
        double ov = __shfl_xor(v2, off);
        int oi = __shfl_xor(ie2, off);
        if (ov > v2 || (ov == v2 && oi < ie2)) { v2 = ov; ie2 = oi; }
    }
    int e2 = ie2;
    if (eidx == 0) {
        routes[row] = e1 | (e2 << 3);
        atomicAdd(&cnt[e1], 1);
        atomicAdd(&cnt[e2], 1);
    }
    __syncthreads();
    if (tid < E_) atomicAdd(&part[tid], (float)cnt[tid]);

    // fused x -> bf16 conversion (rows L1/L2-hot from the gate loop)
    const float4* xs = (const float4*)(x + (size_t)blockIdx.x * 32 * F_);
    ushort4* xd = (ushort4*)(xb + (size_t)blockIdx.x * 32 * F_);
    #pragma unroll
    for (int i = 0; i < 16; ++i) {
        float4 xv = xs[tid + i * 256];
        ushort4 o;
        o.x = f2b(xv.x); o.y = f2b(xv.y); o.z = f2b(xv.z); o.w = f2b(xv.w);
        xd[tid + i * 256] = o;
    }
}

// ---------------- K2: fused MoE — one block = 64 rows x ALL 8 experts ----------------
// LDS 81920 B -> exactly 2 blocks/CU (163840 B), grid 512 = one residency round.
//   A region [0,65536): 64 rows x 512 k bf16, staged ONCE (swizzled gll16),
//     resident for all experts. xbf read once from HBM (33.5 MB vs 124 MB).
//   sH region [65536,81920): [64 rows][128 h'] bf16, slot^(row&15) XOR swizzle;
//     GEMM2 runs in two passes (even/odd 32-h-col groups per producer wave).
// GEMM1: zero barriers; B (w1t, L2-hot now that the xbf stream is gone)
//   register-dbuffered one full K-step (32 MFMAs of cover); kk=7 slot
//   prefetches the NEXT expert's first tile (clamped at e=7).
// GEMM2: W2 frags from global (L2-hot), chunk-dbuffered.
// Epilogue per expert: preds write + in-register softmax + gated combine
// (replaces the old k3 kernel entirely).
__global__ __launch_bounds__(256, 2) void k2_moe(const unsigned short* __restrict__ xbf,
                                                 const unsigned short* __restrict__ w1t,
                                                 const unsigned short* __restrict__ w2t,
                                                 const float* __restrict__ b1,
                                                 const float* __restrict__ b2,
                                                 const int* __restrict__ routes,
                                                 float* __restrict__ preds,
                                                 float* __restrict__ combined) {
    __shared__ __align__(16) char smem[81920];
    const int tid = threadIdx.x;
    const int w = tid >> 6, lane = tid & 63;
    const int q = lane >> 4, ln = lane & 15;
    const int rowBase = blockIdx.x * 64;

    // ---- stage the whole 64x512 A-tile once (8 x 8KiB sub-tiles, swizzled slots) ----
    const int sub = lane >> 3;
    const int j8 = (lane & 7) ^ sub;
    const unsigned short* srcA0 = xbf + (size_t)(rowBase + w * 8 + sub) * F_ + 8 * j8;
    char* dstA = smem + w * 1024;
    #pragma unroll
    for (int kk = 0; kk < 8; ++kk) {
        gll16(srcA0 + kk * 64, dstA + kk * 8192);
        gll16(srcA0 + 32 * F_ + kk * 64, dstA + kk * 8192 + 4096);
    }

    const int lrow = w * 16 + ln;
    const int row = rowBase + lrow;
    const int rt = routes[row];

    // B base for expert 0; advances by H_*F_ per expert
    const unsigned short* bb = w1t + (size_t)(w * 64 + ln) * F_ + q * 8;
    bf16x8 bc[2][4], bn[2][4];
    #pragma unroll
    for (int ks2 = 0; ks2 < 2; ++ks2)
        #pragma unroll
        for (int nt = 0; nt < 4; ++nt)
            bc[ks2][nt] = *(const bf16x8*)(bb + nt * 16 * F_ + ks2 * 32);

    f32x4 comb[7];
    #pragma unroll
    for (int mt = 0; mt < 7; ++mt) comb[mt] = (f32x4){0.f, 0.f, 0.f, 0.f};

    const unsigned short* w2b = w2t + (size_t)ln * H_ + q * 8;

    __syncthreads();   // A-tile staged (drains gll16)

    for (int e = 0; e < E_; ++e) {
        float bias1[4];
        #pragma unroll
        for (int nt = 0; nt < 4; ++nt) bias1[nt] = b1[e * H_ + w * 64 + nt * 16 + ln];

        f32x4 acc[4][4];
        #pragma unroll
        for (int i = 0; i < 4; ++i)
            #pragma unroll
            for (int j = 0; j < 4; ++j) acc[i][j] = (f32x4){0.f, 0.f, 0.f, 0.f};

        // ---- GEMM1: 8 K-steps, no barriers; B dbuf one K-step ahead ----
        #pragma unroll
        for (int kk = 0; kk < 8; ++kk) {
            // prefetch: next K-step of this expert, or next expert's chunk 0
            // (clamped to own chunk 0 at e==7 to never read past w1t)
            const size_t pfo = (kk < 7) ? (size_t)(kk + 1) * 64
                                        : ((e < E_ - 1) ? (size_t)H_ * F_ : 0);
            const unsigned short* pf = bb + pfo;
            #pragma unroll
            for (int ks2 = 0; ks2 < 2; ++ks2)
                #pragma unroll
                for (int nt = 0; nt < 4; ++nt)
                    bn[ks2][nt] = *(const bf16x8*)(pf + nt * 16 * F_ + ks2 * 32);
            #pragma unroll
            for (int ks = 0; ks < 2; ++ks) {
                const int slot = ((ks * 4 + q) ^ (ln & 7)) * 16;
                bf16x8 af[4];
                #pragma unroll
                for (int mt = 0; mt < 4; ++mt)
                    af[mt] = *(const bf16x8*)(smem + kk * 8192 + (mt * 16 + ln) * 128 + slot);
                #pragma unroll
                for (int mt = 0; mt < 4; ++mt)
                    #pragma unroll
                    for (int nt = 0; nt < 4; ++nt)
                        acc[mt][nt] = __builtin_amdgcn_mfma_f32_16x16x32_bf16(af[mt], bc[ks][nt], acc[mt][nt], 0, 0, 0);
            }
            #pragma unroll
            for (int ks2 = 0; ks2 < 2; ++ks2)
                #pragma unroll
                for (int nt = 0; nt < 4; ++nt)
                    bc[ks2][nt] = bn[ks2][nt];
        }
        bb += (size_t)H_ * F_;

        // prefetch W2 chunk 0 (hidden under sH writes + barrier)
        bf16x8 wv[2][7];
        #pragma unroll
        for (int mt = 0; mt < 7; ++mt)
            wv[0][mt] = *(const bf16x8*)(w2b + mt * 16 * H_);

        __syncthreads();   // bar D: previous expert's pass-1 sH reads all done

        // sH even-pass writes: h-cols (h mod 64) in [0,32)  (nt = 0,1)
        #pragma unroll
        for (int mt = 0; mt < 4; ++mt)
            #pragma unroll
            for (int nt2 = 0; nt2 < 2; ++nt2)
                #pragma unroll
                for (int r2 = 0; r2 < 4; ++r2) {
                    int rr = mt * 16 + q * 4 + r2;
                    int hp = w * 32 + nt2 * 16 + ln;
                    float v = fmaxf(acc[mt][nt2][r2] + bias1[nt2], 0.0f);
                    *(unsigned short*)(smem + 65536 + rr * 256 +
                                       (((hp >> 3) ^ (rr & 15)) << 4) + ((hp & 7) << 1)) = f2b(v);
                }
        __syncthreads();   // bar A: even sH visible

        f32x4 acc2[7];
        #pragma unroll
        for (int mt = 0; mt < 7; ++mt) acc2[mt] = (f32x4){0.f, 0.f, 0.f, 0.f};

        // GEMM2 pass 0: chunks c = 0,2,4,6 ; after j=3 prefetch c=1 (pass 1)
        #pragma unroll
        for (int j = 0; j < 4; ++j) {
            const int nc = (j < 3) ? (2 * (j + 1)) * 32 : 32;
            #pragma unroll
            for (int mt = 0; mt < 7; ++mt)
                wv[(j + 1) & 1][mt] = *(const bf16x8*)(w2b + mt * 16 * H_ + nc);
            bf16x8 hb = *(const bf16x8*)(smem + 65536 + lrow * 256 + (((4 * j + q) ^ ln) << 4));
            #pragma unroll
            for (int mt = 0; mt < 7; ++mt)
                acc2[mt] = __builtin_amdgcn_mfma_f32_16x16x32_bf16(wv[j & 1][mt], hb, acc2[mt], 0, 0, 0);
        }
        __syncthreads();   // bar B: pass-0 reads done

        // sH odd-pass writes: h-cols (h mod 64) in [32,64)  (nt = 2,3)
        #pragma unroll
        for (int mt = 0; mt < 4; ++mt)
            #pragma unroll
            for (int nt2 = 2; nt2 < 4; ++nt2)
                #pragma unroll
                for (int r2 = 0; r2 < 4; ++r2) {
                    int rr = mt * 16 + q * 4 + r2;
                    int hp = w * 32 + (nt2 - 2) * 16 + ln;
                    float v = fmaxf(acc[mt][nt2][r2] + bias1[nt2], 0.0f);
                    *(unsigned short*)(smem + 65536 + rr * 256 +
                                       (((hp >> 3) ^ (rr & 15)) << 4) + ((hp & 7) << 1)) = f2b(v);
                }
        __syncthreads();   // bar C: odd sH visible

        // GEMM2 pass 1: chunks c = 1,3,5,7
        #pragma unroll
        for (int j = 0; j < 4; ++j) {
            if (j < 3) {
                const int nc = (2 * (j + 1) + 1) * 32;
                #pragma unroll
                for (int mt = 0; mt < 7; ++mt)
                    wv[(j + 1) & 1][mt] = *(const bf16x8*)(w2b + mt * 16 * H_ + nc);
            }
            bf16x8 hb = *(const bf16x8*)(smem + 65536 + lrow * 256 + (((4 * j + q) ^ ln) << 4));
            #pragma unroll
            for (int mt = 0; mt < 7; ++mt)
                acc2[mt] = __builtin_amdgcn_mfma_f32_16x16x32_bf16(wv[j & 1][mt], hb, acc2[mt], 0, 0, 0);
        }
        w2b += (size_t)CP * H_;

        // ---- preds write + in-register softmax + gated combine (replaces k3) ----
        // lane holds c = mt*16 + q*4 + {0..3} for row = rowBase + w*16 + ln
        float mx = -1e30f;
        #pragma unroll
        for (int mt = 0; mt < 7; ++mt) {
            const int c0 = mt * 16 + q * 4;
            if (c0 + 3 < C_) {
                f32x4 bias = *(const f32x4*)(b2 + e * C_ + c0);
                acc2[mt] += bias;
                *(f32x4*)(preds + ((size_t)e * B_ + row) * C_ + c0) = acc2[mt];
                #pragma unroll
                for (int r2 = 0; r2 < 4; ++r2) mx = fmaxf(mx, acc2[mt][r2]);
            }
        }
        mx = fmaxf(mx, __shfl_xor(mx, 16));
        mx = fmaxf(mx, __shfl_xor(mx, 32));
        float s = 0.f;
        #pragma unroll
        for (int mt = 0; mt < 7; ++mt) {
            const int c0 = mt * 16 + q * 4;
            if (c0 + 3 < C_) {
                #pragma unroll
                for (int r2 = 0; r2 < 4; ++r2) {
                    acc2[mt][r2] = __expf(acc2[mt][r2] - mx);
                    s += acc2[mt][r2];
                }
            }
        }
        s += __shfl_xor(s, 16);
        s += __shfl_xor(s, 32);
        const float fac = 0.5f * ((((rt & 7) == e) ? 1.f : 0.f) +
                                  ((((rt >> 3) & 7) == e) ? 1.f : 0.f)) / s;
        #pragma unroll
        for (int mt = 0; mt < 7; ++mt) {
            const int c0 = mt * 16 + q * 4;
            if (c0 + 3 < C_) comb[mt] += acc2[mt] * fac;
        }
    }

    // final combined write
    #pragma unroll
    for (int mt = 0; mt < 7; ++mt) {
        const int c0 = mt * 16 + q * 4;
        if (c0 + 3 < C_)
            *(f32x4*)(combined + (size_t)row * C_ + c0) = comb[mt];
    }
}

extern "C" void kernel_launch(void* const* d_in, const int* in_sizes, int n_in,
                              void* d_out, int out_size, void* d_ws, size_t ws_size,
                              hipStream_t stream) {
    (void)in_sizes; (void)n_in; (void)out_size;
    const float* x  = (const float*)d_in[0];
    const float* W1 = (const float*)d_in[1];
    const float* b1 = (const float*)d_in[2];
    const float* W2 = (const float*)d_in[3];
    const float* b2 = (const float*)d_in[4];
    const float* Wg = (const float*)d_in[5];
    // d_in[6] = k (always 2 per setup)

    float* out = (float*)d_out;
    float* combined = out;                                          // [B][C]
    float* preds = out + (size_t)B_ * C_;                           // [E][B][C]
    float* part  = out + (size_t)B_ * C_ + (size_t)E_ * B_ * C_;    // [E]

    char* ws = (char*)d_ws;
    unsigned short* xbf = (unsigned short*)ws;                      // 33,554,432 B
    unsigned short* w1t = (unsigned short*)(ws + 33554432);         //  2,097,152 B
    unsigned short* w2t = (unsigned short*)(ws + 35651584);         //    458,752 B
    int* routes = (int*)(ws + 36110336);                            //    131,072 B
    if (ws_size < 36241408) return;  // need ~36.3 MB scratch

    hipMemsetAsync(part, 0, E_ * sizeof(float), stream);
    k0_tr_w1<<<dim3(F_ / 32, H_ / 32, E_), dim3(32, 8), 0, stream>>>(W1, w1t);
    k0_cvt_w2<<<(E_ * CP * H_ + 255) / 256, 256, 0, stream>>>(W2, w2t);
    k1_gate<<<B_ / 32, 256, 0, stream>>>(x, Wg, xbf, routes, part);
    k2_moe<<<dim3(B_ / 64), 256, 0, stream>>>(xbf, w1t, w2t, b1, b2, routes, preds, combined);
}